// Round 13
// baseline (585.421 us; speedup 1.0000x reference)
//
#include <hip/hip_runtime.h>
#include <cstddef>

#define T_STEPS  512
#define D_IN     5
#define NB       16      // batch elements per block
#define NTHREADS 1024    // 16 waves; each wave owns M-tile w of BOTH layers
#define LOG2E    1.4426950408889634f

typedef __attribute__((ext_vector_type(8))) short bf16x8;   // 8 bf16 (4 regs)
typedef __attribute__((ext_vector_type(4))) float f32x4;    // MFMA C/D

// Builtin MFMA: the compiler's hazard recognizer inserts all required wait
// states (inline-asm MFMA is invisible to it -- the likely cause of the
// allocation-dependent corruption in R9/R10/R12's asm variants).
#define MFMA(A, B, C) __builtin_amdgcn_mfma_f32_16x16x32_bf16((A), (B), (C), 0, 0, 0)

// Weights pre-scaled by log2e (2*log2e for g-gate rows): activations use
// v_exp_f32 (2^x) directly; negation is a free input modifier.
__device__ __forceinline__ float rcp1p(float t) {           // 1/(1+t)
    return __builtin_amdgcn_rcpf(1.0f + t);
}
__device__ __forceinline__ float sig2(float a) {            // sigmoid, a = log2e*x
    return rcp1p(__builtin_amdgcn_exp2f(-a));
}
__device__ __forceinline__ float tanh2(float a) {           // tanh, a = 2*log2e*x
    return 1.0f - 2.0f * rcp1p(__builtin_amdgcn_exp2f(a));
}

__device__ __forceinline__ unsigned short f2bf(float f) {   // RTNE fp32->bf16 bits
    unsigned int u = __float_as_uint(f);
    u += 0x7FFFu + ((u >> 16) & 1u);
    return (unsigned short)(u >> 16);
}
__device__ __forceinline__ float bf2f(unsigned short h) {
    return __uint_as_float(((unsigned int)h) << 16);
}
__device__ __forceinline__ void split8(const float* wv, bf16x8& hi, bf16x8& lo) {
    #pragma unroll
    for (int j = 0; j < 8; ++j) {
        unsigned short h = f2bf(wv[j]);
        unsigned short l = f2bf(wv[j] - bf2f(h));
        hi[j] = (short)h;
        lo[j] = (short)l;
    }
}

// h-plane swizzle: row = 128 u16 = 16 x 16B blocks; block j of row n lives at
// j ^ (n & 7). b128 reads conflict-free; b16 writes 2/4-way (accepted).
__device__ __forceinline__ int hswz(int n, int col) {
    return (((col >> 3) ^ (n & 7)) << 3) | (col & 7);
}

// R8-verified row permutation: MFMA A-row m of tile w -> unit u = w*4 + (m>>2),
// gate = m&3 (orig weight row gate*64+u). C/D layout (col=lane&15,
// row=quad*4+r) gives lane acc = (i,f,g,o) of (u=w*4+quad, b=n16):
// register-local cell update. Even waves: L0 chain -> L1 part1 -> epi0 ->
// L1 part2 -> epi1. Odd waves: phase-reversed (stagger matrix vs VALU/LDS
// phases across the 4 waves/SIMD).

__global__ __launch_bounds__(NTHREADS, 4)
void lstm_stack_mfma10(const float* __restrict__ x,
                       const float* __restrict__ W_ih0,
                       const float* __restrict__ W_hh0,
                       const float* __restrict__ b_ih0,
                       const float* __restrict__ b_hh0,
                       const float* __restrict__ W_ih1,
                       const float* __restrict__ W_hh1,
                       const float* __restrict__ b_ih1,
                       const float* __restrict__ b_hh1,
                       const float* __restrict__ W1,
                       const float* __restrict__ b1,
                       const float* __restrict__ W2,
                       const float* __restrict__ b2,
                       float* __restrict__ out)
{
    __shared__ alignas(16) unsigned short h_hi[2][NB][128];  // k 0..63=h1, 64..127=h2 (swizzled)
    __shared__ alignas(16) unsigned short x_pack[2][NB][40]; // [x_hi(5)|x_lo(5)|x_hi(5)|0..]
    __shared__ alignas(16) float h2f[NB][68];   // exact fp32 h2(T-1) for FC head
    __shared__ alignas(16) float zb[NB][36];    // FC-head z buffer

    const int tid  = threadIdx.x;
    const int b0   = blockIdx.x * NB;
    const int w    = tid >> 6;        // wave 0..15 = M-tile index (both layers)
    const int lane = tid & 63;
    const int n16  = lane & 15;       // A row (within tile) / B col / C col
    const int quad = lane >> 4;       // A k-group / C row-group

    // ---------------- persistent register state ----------------
    bf16x8 aXp;                       // L0 packed x-weights [Wx_hi|Wx_hi|Wx_lo]
    bf16x8 a0[4];                     // L0 h1: [Whi k0, Whi k1, Wlo k0, Wlo k1]
    bf16x8 a1[8];                     // L1 [h1;h2]: [Whi k0..3, Wlo k0..3]
    f32x4  bc0, bc1;                  // bias C-operands
    float  c0 = 0.f, c1 = 0.f;        // cell state (u = w*4+quad, b = n16)

    {
        const int u_a = w * 4 + (n16 >> 2);   // permuted u of this A row
        const int g_a = n16 & 3;              // gate of this A row (i,f,g,o)
        const int r0  = g_a * 64 + u_a;       // original weight row
        const float sc = (g_a == 2) ? 2.0f * LOG2E : LOG2E;   // exp2 pre-scale
        float wv[8];
        // packed x K-tile: slots 0-4 Wx_hi, 5-9 Wx_hi, 10-14 Wx_lo, 15.. 0
        #pragma unroll
        for (int j = 0; j < 8; ++j) {
            const int k = quad * 8 + j;
            float v = 0.f;
            if (k < 2 * D_IN) {
                const float wf = sc * W_ih0[r0 * D_IN + (k < D_IN ? k : k - D_IN)];
                v = bf2f(f2bf(wf));
            } else if (k < 3 * D_IN) {
                const float wf = sc * W_ih0[r0 * D_IN + (k - 2 * D_IN)];
                v = wf - bf2f(f2bf(wf));
            }
            wv[j] = v;
        }
        bf16x8 dum;
        split8(wv, aXp, dum);         // values already bf16-exact
        #pragma unroll
        for (int kt = 0; kt < 2; ++kt) {
            #pragma unroll
            for (int j = 0; j < 8; ++j)
                wv[j] = sc * W_hh0[r0 * 64 + kt * 32 + quad * 8 + j];
            split8(wv, a0[kt], a0[2 + kt]);
        }
        #pragma unroll
        for (int kt = 0; kt < 4; ++kt) {
            const int kg = kt * 32 + quad * 8;
            #pragma unroll
            for (int j = 0; j < 8; ++j)
                wv[j] = sc * ((kg < 64) ? W_ih1[r0 * 64 + kg + j]
                                        : W_hh1[r0 * 64 + (kg - 64) + j]);
            split8(wv, a1[kt], a1[4 + kt]);
        }
        const int u_c = w * 4 + quad;
        #pragma unroll
        for (int r = 0; r < 4; ++r) {
            const float scr = (r == 2) ? 2.0f * LOG2E : LOG2E;
            bc0[r] = scr * (b_ih0[r * 64 + u_c] + b_hh0[r * 64 + u_c]);
            bc1[r] = scr * (b_ih1[r * 64 + u_c] + b_hh1[r * 64 + u_c]);
        }
    }

    // ---------------- LDS init ----------------
    for (int i = tid; i < 2 * NB * 128; i += NTHREADS) (&h_hi[0][0][0])[i] = 0;
    for (int i = tid; i < 2 * NB * 40; i += NTHREADS) (&x_pack[0][0][0])[i] = 0;
    __syncthreads();
    const int xb = tid / D_IN, xd = tid % D_IN;   // x-staging role (tid < 80)
    const bool xrole = (tid < NB * D_IN);
    if (xrole) {   // x(t=0) into buffer 0
        const float xv = x[((size_t)(b0 + xb) * T_STEPS) * D_IN + xd];
        const unsigned short xh = f2bf(xv);
        const unsigned short xl = f2bf(xv - bf2f(xh));
        x_pack[0][xb][xd]             = xh;
        x_pack[0][xb][D_IN + xd]      = xl;
        x_pack[0][xb][2 * D_IN + xd]  = xh;
    }
    __syncthreads();

    const int u_c = w * 4 + quad;     // this lane's unit index, b = n16

    // step s: reads buf[s&1] = {h1(s-1), h2(s-2), x(s)}; writes h1(s),
    // h2(s-1), x(s+1) into buf[(s+1)&1]; one barrier per step.
    #pragma unroll 1
    for (int s = 0; s <= T_STEPS; ++s) {
        const int rb = s & 1, wbuf = rb ^ 1;

        float xv = 0.f;   // prefetch x(s+1)
        if (xrole && (s + 1) < T_STEPS)
            xv = x[((size_t)(b0 + xb) * T_STEPS + (s + 1)) * D_IN + xd];

        const bf16x8 bxp  = *reinterpret_cast<const bf16x8*>(&x_pack[rb][n16][quad * 8]);
        bf16x8 bhh[4];
        #pragma unroll
        for (int kt = 0; kt < 4; ++kt)
            bhh[kt] = *reinterpret_cast<const bf16x8*>(
                &h_hi[rb][n16][((kt * 4 + quad) ^ (n16 & 7)) * 8]);

        // R8-verbatim epilogues (arithmetic untouched)
        auto epi0 = [&](const f32x4& acc) {
            const float i_ = sig2(acc[0]);
            const float f_ = sig2(acc[1]);
            const float g_ = tanh2(acc[2]);
            const float o_ = sig2(acc[3]);
            const float c  = f_ * c0 + i_ * g_;
            c0 = c;
            const float h  = o_ * tanh2(c * (2.0f * LOG2E));
            h_hi[wbuf][n16][hswz(n16, u_c)] = f2bf(h);
        };
        auto epi1 = [&](const f32x4& acc, bool fcw) {
            const float i_ = sig2(acc[0]);
            const float f_ = sig2(acc[1]);
            const float g_ = tanh2(acc[2]);
            const float o_ = sig2(acc[3]);
            const float c  = f_ * c1 + i_ * g_;
            c1 = c;
            const float h  = o_ * tanh2(c * (2.0f * LOG2E));
            h_hi[wbuf][n16][hswz(n16, 64 + u_c)] = f2bf(h);
            if (fcw) h2f[n16][u_c] = h;   // exact h2(T-1) for FC head
        };

        f32x4 acc0, acc1;
        if ((w & 1) == 0) {
            // ---- even: R8 order ----
            acc0 = MFMA(aXp, bxp, bc0);        // bias + all 3 x split terms
            acc0 = MFMA(a0[0], bhh[0], acc0);  // Whi . h1
            acc0 = MFMA(a0[1], bhh[1], acc0);
            acc0 = MFMA(a0[2], bhh[0], acc0);  // Wlo . h1
            acc0 = MFMA(a0[3], bhh[1], acc0);
            acc1 = MFMA(a1[0], bhh[0], bc1);   // Whi . [h1;h2]
            acc1 = MFMA(a1[1], bhh[1], acc1);
            acc1 = MFMA(a1[2], bhh[2], acc1);
            acc1 = MFMA(a1[3], bhh[3], acc1);
            if (s < T_STEPS) epi0(acc0);
            acc1 = MFMA(a1[4], bhh[0], acc1);  // Wlo . [h1;h2]
            acc1 = MFMA(a1[5], bhh[1], acc1);
            acc1 = MFMA(a1[6], bhh[2], acc1);
            acc1 = MFMA(a1[7], bhh[3], acc1);
            if (s > 0) epi1(acc1, s == T_STEPS);
        } else {
            // ---- odd: phase-reversed ----
            acc1 = MFMA(a1[0], bhh[0], bc1);   // Whi . [h1;h2]
            acc1 = MFMA(a1[1], bhh[1], acc1);
            acc1 = MFMA(a1[2], bhh[2], acc1);
            acc1 = MFMA(a1[3], bhh[3], acc1);
            acc1 = MFMA(a1[4], bhh[0], acc1);  // Wlo . [h1;h2]
            acc1 = MFMA(a1[5], bhh[1], acc1);
            acc1 = MFMA(a1[6], bhh[2], acc1);
            acc1 = MFMA(a1[7], bhh[3], acc1);
            if (s > 0) epi1(acc1, s == T_STEPS);
            acc0 = MFMA(aXp, bxp, bc0);        // bias + all 3 x split terms
            acc0 = MFMA(a0[0], bhh[0], acc0);  // Whi . h1
            acc0 = MFMA(a0[1], bhh[1], acc0);
            acc0 = MFMA(a0[2], bhh[0], acc0);  // Wlo . h1
            acc0 = MFMA(a0[3], bhh[1], acc0);
            if (s < T_STEPS) epi0(acc0);
        }

        if (xrole && (s + 1) < T_STEPS) {   // stage x(s+1) packed
            const unsigned short xh = f2bf(xv);
            const unsigned short xl = f2bf(xv - bf2f(xh));
            x_pack[wbuf][xb][xd]            = xh;
            x_pack[wbuf][xb][D_IN + xd]     = xl;
            x_pack[wbuf][xb][2 * D_IN + xd] = xh;
        }
        __syncthreads();
    }

    // ---------------- FC head: relu(h2_T @ W1^T + b1) @ W2^T + b2 ----------------
    if (tid < 512) {
        const int bb = tid >> 5;            // 0..15
        const int k  = tid & 31;            // 0..31
        float a = b1[k];
        #pragma unroll 16
        for (int j = 0; j < 64; ++j)
            a = fmaf(W1[k * 64 + j], h2f[bb][j], a);
        zb[bb][k] = fmaxf(a, 0.0f);
    }
    __syncthreads();
    if (tid < NB) {
        float a = b2[0];
        #pragma unroll
        for (int k = 0; k < 32; ++k) a = fmaf(W2[k], zb[tid][k], a);
        out[b0 + tid] = a;
    }
}

extern "C" void kernel_launch(void* const* d_in, const int* in_sizes, int n_in,
                              void* d_out, int out_size, void* d_ws, size_t ws_size,
                              hipStream_t stream) {
    (void)in_sizes; (void)n_in; (void)d_ws; (void)ws_size;
    const float* xp     = (const float*)d_in[0];
    const float* W_ih0  = (const float*)d_in[1];
    const float* W_hh0  = (const float*)d_in[2];
    const float* b_ih0  = (const float*)d_in[3];
    const float* b_hh0  = (const float*)d_in[4];
    const float* W_ih1  = (const float*)d_in[5];
    const float* W_hh1  = (const float*)d_in[6];
    const float* b_ih1  = (const float*)d_in[7];
    const float* b_hh1  = (const float*)d_in[8];
    const float* W1     = (const float*)d_in[9];
    const float* b1     = (const float*)d_in[10];
    const float* W2     = (const float*)d_in[11];
    const float* b2     = (const float*)d_in[12];
    float* outp = (float*)d_out;

    const int nblocks = out_size / NB;   // 4096/16 = 256, one block per CU
    hipLaunchKernelGGL(lstm_stack_mfma10, dim3(nblocks), dim3(NTHREADS), 0, stream,
                       xp, W_ih0, W_hh0, b_ih0, b_hh0,
                       W_ih1, W_hh1, b_ih1, b_hh1,
                       W1, b1, W2, b2, outp);
}